// Round 1
// baseline (762.469 us; speedup 1.0000x reference)
//
#include <hip/hip_runtime.h>

#define BATCH 16384
#define INF 768
#define OUTF 768
#define KTOT (9 * 768)   // 8 RBF slabs + 1 silu slab
#define BM 128
#define BN 128
#define BK 64
#define PK (BK + 8)      // +8 bf16 pad -> 144B row stride, breaks bank conflicts

typedef __bf16 bf16x8 __attribute__((ext_vector_type(8)));
typedef float f32x4 __attribute__((ext_vector_type(4)));

__device__ __forceinline__ unsigned short f2bf(float f) {
  unsigned u = __builtin_bit_cast(unsigned, f);
  u += 0x7fffu + ((u >> 16) & 1u);     // round-to-nearest-even
  return (unsigned short)(u >> 16);
}

__device__ __forceinline__ float phi_f(float x, float g) {
  float z = (x - g) * 1.75f;           // 1/h, h = 4/7
  return __expf(-z * z);
}

__device__ __forceinline__ float silu_f(float x) {
  return x / (1.f + __expf(-x));
}

__global__ __launch_bounds__(256, 2) void kan_gemm(
    const float* __restrict__ x, const float* __restrict__ w_b,
    const float* __restrict__ w_s, const float* __restrict__ c,
    float* __restrict__ out) {
  __shared__ unsigned short As[BM][PK];
  __shared__ unsigned short Bs[BN][PK];

  const int bid = blockIdx.x;
  const int cb = bid % (OUTF / BN);    // 6 col-blocks
  const int rb = bid / (OUTF / BN);    // 128 row-blocks
  const int row0 = rb * BM, col0 = cb * BN;

  const int t = threadIdx.x;
  const int lane = t & 63;
  const int w = t >> 6;
  const int wr = w >> 1, wc = w & 1;   // 2x2 waves, 64x64 each
  const int lrow = lane & 15, lhi = lane >> 4;

  f32x4 acc[4][4];
#pragma unroll
  for (int m = 0; m < 4; ++m)
#pragma unroll
    for (int n = 0; n < 4; ++n)
      acc[m][n] = (f32x4){0.f, 0.f, 0.f, 0.f};

  const int rsub = t >> 4;   // 0..15
  const int k4 = t & 15;     // float4 column within tile

  for (int kt = 0; kt < KTOT / BK; ++kt) {   // 108 K-tiles
    const int a = kt / (INF / BK);           // slab index, uniform per tile
    const int i0 = (kt % (INF / BK)) * BK;
    const float ga = -2.f + (float)a * (4.f / 7.f);

#pragma unroll
    for (int p = 0; p < 8; ++p) {
      const int r = p * 16 + rsub;
      // ---- A tile: expand x on the fly ----
      const float4 xv = *(const float4*)(x + (size_t)(row0 + r) * INF + i0 + k4 * 4);
      ushort4 av;
      if (a < 8) {
        av.x = f2bf(phi_f(xv.x, ga));
        av.y = f2bf(phi_f(xv.y, ga));
        av.z = f2bf(phi_f(xv.z, ga));
        av.w = f2bf(phi_f(xv.w, ga));
      } else {
        av.x = f2bf(silu_f(xv.x));
        av.y = f2bf(silu_f(xv.y));
        av.z = f2bf(silu_f(xv.z));
        av.w = f2bf(silu_f(xv.w));
      }
      *(ushort4*)&As[r][k4 * 4] = av;

      // ---- B tile: fold w_s into c, or take w_b for the silu slab ----
      ushort4 bv;
      if (a < 8) {
        const float4 cv = *(const float4*)(c + ((size_t)a * OUTF + col0 + r) * INF + i0 + k4 * 4);
        const float4 wv = *(const float4*)(w_s + (size_t)(col0 + r) * INF + i0 + k4 * 4);
        bv.x = f2bf(cv.x * wv.x);
        bv.y = f2bf(cv.y * wv.y);
        bv.z = f2bf(cv.z * wv.z);
        bv.w = f2bf(cv.w * wv.w);
      } else {
        const float4 bbv = *(const float4*)(w_b + (size_t)(col0 + r) * INF + i0 + k4 * 4);
        bv.x = f2bf(bbv.x);
        bv.y = f2bf(bbv.y);
        bv.z = f2bf(bbv.z);
        bv.w = f2bf(bbv.w);
      }
      *(ushort4*)&Bs[r][k4 * 4] = bv;
    }
    __syncthreads();

#pragma unroll
    for (int kk = 0; kk < 2; ++kk) {
      bf16x8 af[4], bfr[4];
#pragma unroll
      for (int m = 0; m < 4; ++m)
        af[m] = *(const bf16x8*)&As[wr * 64 + m * 16 + lrow][kk * 32 + lhi * 8];
#pragma unroll
      for (int n = 0; n < 4; ++n)
        bfr[n] = *(const bf16x8*)&Bs[wc * 64 + n * 16 + lrow][kk * 32 + lhi * 8];
#pragma unroll
      for (int m = 0; m < 4; ++m)
#pragma unroll
        for (int n = 0; n < 4; ++n)
          acc[m][n] = __builtin_amdgcn_mfma_f32_16x16x32_bf16(af[m], bfr[n], acc[m][n], 0, 0, 0);
    }
    __syncthreads();
  }

  // ---- epilogue: C/D layout col=lane&15, row=(lane>>4)*4+r ----
#pragma unroll
  for (int m = 0; m < 4; ++m) {
#pragma unroll
    for (int n = 0; n < 4; ++n) {
      const int row = row0 + wr * 64 + m * 16 + lhi * 4;
      const int col = col0 + wc * 64 + n * 16 + lrow;
#pragma unroll
      for (int r = 0; r < 4; ++r)
        out[(size_t)(row + r) * OUTF + col] = acc[m][n][r];
    }
  }
}

extern "C" void kernel_launch(void* const* d_in, const int* in_sizes, int n_in,
                              void* d_out, int out_size, void* d_ws, size_t ws_size,
                              hipStream_t stream) {
  const float* x   = (const float*)d_in[0];
  const float* w_b = (const float*)d_in[1];
  const float* w_s = (const float*)d_in[2];
  const float* c   = (const float*)d_in[3];
  float* out = (float*)d_out;

  dim3 grid((BATCH / BM) * (OUTF / BN));  // 768 blocks
  kan_gemm<<<grid, 256, 0, stream>>>(x, w_b, w_s, c, out);
}

// Round 2
// 275.675 us; speedup vs baseline: 2.7658x; 2.7658x over previous
//
#include <hip/hip_runtime.h>

#define BATCH 16384
#define INF 768
#define OUTF 768
#define NSLAB 9                  // 8 RBF slabs + 1 silu slab
#define KTOT (NSLAB * INF)       // 6912
#define BM 128
#define BN 128
#define BK 64
#define PK (BK + 8)              // A-tile pad: 144B row stride
#define KB_TILES (INF / BK)      // 12 i0-blocks

typedef __bf16 bf16x8 __attribute__((ext_vector_type(8)));
typedef float f32x4 __attribute__((ext_vector_type(4)));
typedef unsigned short ushort8v __attribute__((ext_vector_type(8)));

__device__ __forceinline__ unsigned short f2bf(float f) {
  unsigned u = __builtin_bit_cast(unsigned, f);
  u += 0x7fffu + ((u >> 16) & 1u);     // round-to-nearest-even
  return (unsigned short)(u >> 16);
}

__device__ __forceinline__ float phi_f(float x, float g) {
  float z = (x - g) * 1.75f;           // 1/h, h = 4/7
  return __expf(-z * z);
}

__device__ __forceinline__ float silu_f(float x) {
  return x / (1.f + __expf(-x));
}

__device__ __forceinline__ void gload_lds16(const void* g, void* l) {
  __builtin_amdgcn_global_load_lds(
      (const __attribute__((address_space(1))) unsigned int*)g,
      (__attribute__((address_space(3))) unsigned int*)l, 16, 0, 0);
}

// ---------------- kernel 1: build W_ext (bf16) into workspace ----------------
// Bext[o][k], k = a*768 + i; a<8: c[a,o,i]*w_s[o,i]; a==8: w_b[o,i].
__global__ __launch_bounds__(256) void build_bext(
    const float* __restrict__ w_b, const float* __restrict__ w_s,
    const float* __restrict__ c, unsigned short* __restrict__ bext) {
  const int tid = blockIdx.x * 256 + threadIdx.x;
  const int o = tid / (KTOT / 8);
  const int k = (tid - o * (KTOT / 8)) * 8;
  const int a = k / INF;               // 768 % 8 == 0 -> uniform over the 8 elems
  const int i = k - a * INF;
  float4 v0, v1;
  if (a < 8) {
    const float* cp = c + ((size_t)(a * OUTF + o)) * INF + i;
    const float* wp = w_s + (size_t)o * INF + i;
    const float4 c0 = *(const float4*)cp, c1 = *(const float4*)(cp + 4);
    const float4 s0 = *(const float4*)wp, s1 = *(const float4*)(wp + 4);
    v0 = make_float4(c0.x * s0.x, c0.y * s0.y, c0.z * s0.z, c0.w * s0.w);
    v1 = make_float4(c1.x * s1.x, c1.y * s1.y, c1.z * s1.z, c1.w * s1.w);
  } else {
    const float* bp = w_b + (size_t)o * INF + i;
    v0 = *(const float4*)bp;
    v1 = *(const float4*)(bp + 4);
  }
  ushort8v r;
  r[0] = f2bf(v0.x); r[1] = f2bf(v0.y); r[2] = f2bf(v0.z); r[3] = f2bf(v0.w);
  r[4] = f2bf(v1.x); r[5] = f2bf(v1.y); r[6] = f2bf(v1.z); r[7] = f2bf(v1.w);
  *(ushort8v*)(bext + (size_t)o * KTOT + k) = r;
}

// ---------------- kernel 2: MFMA GEMM, A on the fly, B via global_load_lds ----
__global__ __launch_bounds__(256, 3) void kan_gemm2(
    const float* __restrict__ x, const unsigned short* __restrict__ bext,
    float* __restrict__ out) {
  __shared__ unsigned short As[BM][PK];      // padded, ds_write staged
  __shared__ unsigned short BsF[BN * BK];    // linear, global_load_lds staged (XOR swz)

  // bijective XCD swizzle: 768 = 8 * 96 (r == 0)
  const int orig = blockIdx.x;
  const int bid = (orig & 7) * 96 + (orig >> 3);
  const int cb = bid / (BATCH / BM);         // cb-major: each XCD chunk shares cb
  const int rb = bid - cb * (BATCH / BM);
  const int row0 = rb * BM, col0 = cb * BN;

  const int t = threadIdx.x;
  const int lane = t & 63;
  const int w = t >> 6;
  const int wr = w >> 1, wc = w & 1;         // 2x2 waves, 64x64 each
  const int lrow = lane & 15, lhi = lane >> 4;
  const int rgrp = lane >> 3, ch = lane & 7; // B staging: 8 rows x 8 chunks / issue

  f32x4 acc[4][4];
#pragma unroll
  for (int m = 0; m < 4; ++m)
#pragma unroll
    for (int n = 0; n < 4; ++n)
      acc[m][n] = (f32x4){0.f, 0.f, 0.f, 0.f};

  const int rsub = t >> 4;   // 0..15 (A staging row within 16-row group)
  const int k4 = t & 15;     // float4 column within tile

  // B staging addresses: lane's global src pre-swizzled (chunk ^ rgrp) so the
  // linear LDS write realizes the XOR layout; ds_read applies the same XOR.
  const unsigned short* gB0 =
      bext + (size_t)(col0 + w * 32 + rgrp) * KTOT + (size_t)(ch ^ rgrp) * 8;
  unsigned short* ldsB0 = &BsF[w * 2048];

  for (int ib = 0; ib < KB_TILES; ++ib) {
    const int i0 = ib * BK;
    float4 xr[8];
#pragma unroll
    for (int p = 0; p < 8; ++p)
      xr[p] = *(const float4*)(x + (size_t)(row0 + p * 16 + rsub) * INF + i0 + k4 * 4);

    for (int a = 0; a < NSLAB; ++a) {
      const int kt = a * KB_TILES + ib;
      // ---- B tile: 4 async direct-to-LDS issues per wave ----
      const unsigned short* gB = gB0 + (size_t)kt * BK;
#pragma unroll
      for (int q = 0; q < 4; ++q)
        gload_lds16(gB + (size_t)q * 8 * KTOT, ldsB0 + q * 512);

      // ---- A tile: expand x from registers ----
      const float ga = -2.f + (float)a * (4.f / 7.f);
#pragma unroll
      for (int p = 0; p < 8; ++p) {
        const float4 xv = xr[p];
        ushort4 av;
        if (a < 8) {
          av.x = f2bf(phi_f(xv.x, ga));
          av.y = f2bf(phi_f(xv.y, ga));
          av.z = f2bf(phi_f(xv.z, ga));
          av.w = f2bf(phi_f(xv.w, ga));
        } else {
          av.x = f2bf(silu_f(xv.x));
          av.y = f2bf(silu_f(xv.y));
          av.z = f2bf(silu_f(xv.z));
          av.w = f2bf(silu_f(xv.w));
        }
        *(ushort4*)&As[p * 16 + rsub][k4 * 4] = av;
      }
      __syncthreads();   // drains vmcnt (global_load_lds) + lgkmcnt (ds_write)

#pragma unroll
      for (int kk = 0; kk < 2; ++kk) {
        bf16x8 af[4], bfr[4];
#pragma unroll
        for (int m = 0; m < 4; ++m)
          af[m] = *(const bf16x8*)&As[wr * 64 + m * 16 + lrow][kk * 32 + lhi * 8];
#pragma unroll
        for (int n = 0; n < 4; ++n) {
          const int rowB = wc * 64 + n * 16 + lrow;
          const int chB = (kk * 4 + lhi) ^ (lrow & 7);
          bfr[n] = *(const bf16x8*)&BsF[rowB * 64 + chB * 8];
        }
#pragma unroll
        for (int m = 0; m < 4; ++m)
#pragma unroll
          for (int n = 0; n < 4; ++n)
            acc[m][n] = __builtin_amdgcn_mfma_f32_16x16x32_bf16(af[m], bfr[n], acc[m][n], 0, 0, 0);
      }
      __syncthreads();
    }
  }

  // ---- epilogue: C/D layout col=lane&15, row=(lane>>4)*4+r ----
#pragma unroll
  for (int m = 0; m < 4; ++m) {
#pragma unroll
    for (int n = 0; n < 4; ++n) {
      const int row = row0 + wr * 64 + m * 16 + lhi * 4;
      const int col = col0 + wc * 64 + n * 16 + lrow;
#pragma unroll
      for (int r = 0; r < 4; ++r)
        out[(size_t)(row + r) * OUTF + col] = acc[m][n][r];
    }
  }
}

// ---------------- fallback (round-1 kernel) if ws is too small ----------------
__global__ __launch_bounds__(256, 2) void kan_gemm_fb(
    const float* __restrict__ x, const float* __restrict__ w_b,
    const float* __restrict__ w_s, const float* __restrict__ c,
    float* __restrict__ out) {
  __shared__ unsigned short As[BM][PK];
  __shared__ unsigned short Bs[BN][PK];

  const int bid = blockIdx.x;
  const int cb = bid % (OUTF / BN);
  const int rb = bid / (OUTF / BN);
  const int row0 = rb * BM, col0 = cb * BN;

  const int t = threadIdx.x;
  const int lane = t & 63;
  const int w = t >> 6;
  const int wr = w >> 1, wc = w & 1;
  const int lrow = lane & 15, lhi = lane >> 4;

  f32x4 acc[4][4];
#pragma unroll
  for (int m = 0; m < 4; ++m)
#pragma unroll
    for (int n = 0; n < 4; ++n)
      acc[m][n] = (f32x4){0.f, 0.f, 0.f, 0.f};

  const int rsub = t >> 4;
  const int k4 = t & 15;

  for (int kt = 0; kt < KTOT / BK; ++kt) {
    const int a = kt / (INF / BK);
    const int i0 = (kt % (INF / BK)) * BK;
    const float ga = -2.f + (float)a * (4.f / 7.f);

#pragma unroll
    for (int p = 0; p < 8; ++p) {
      const int r = p * 16 + rsub;
      const float4 xv = *(const float4*)(x + (size_t)(row0 + r) * INF + i0 + k4 * 4);
      ushort4 av;
      if (a < 8) {
        av.x = f2bf(phi_f(xv.x, ga)); av.y = f2bf(phi_f(xv.y, ga));
        av.z = f2bf(phi_f(xv.z, ga)); av.w = f2bf(phi_f(xv.w, ga));
      } else {
        av.x = f2bf(silu_f(xv.x)); av.y = f2bf(silu_f(xv.y));
        av.z = f2bf(silu_f(xv.z)); av.w = f2bf(silu_f(xv.w));
      }
      *(ushort4*)&As[r][k4 * 4] = av;

      ushort4 bv;
      if (a < 8) {
        const float4 cv = *(const float4*)(c + ((size_t)a * OUTF + col0 + r) * INF + i0 + k4 * 4);
        const float4 wv = *(const float4*)(w_s + (size_t)(col0 + r) * INF + i0 + k4 * 4);
        bv.x = f2bf(cv.x * wv.x); bv.y = f2bf(cv.y * wv.y);
        bv.z = f2bf(cv.z * wv.z); bv.w = f2bf(cv.w * wv.w);
      } else {
        const float4 bbv = *(const float4*)(w_b + (size_t)(col0 + r) * INF + i0 + k4 * 4);
        bv.x = f2bf(bbv.x); bv.y = f2bf(bbv.y);
        bv.z = f2bf(bbv.z); bv.w = f2bf(bbv.w);
      }
      *(ushort4*)&Bs[r][k4 * 4] = bv;
    }
    __syncthreads();

#pragma unroll
    for (int kk = 0; kk < 2; ++kk) {
      bf16x8 af[4], bfr[4];
#pragma unroll
      for (int m = 0; m < 4; ++m)
        af[m] = *(const bf16x8*)&As[wr * 64 + m * 16 + lrow][kk * 32 + lhi * 8];
#pragma unroll
      for (int n = 0; n < 4; ++n)
        bfr[n] = *(const bf16x8*)&Bs[wc * 64 + n * 16 + lrow][kk * 32 + lhi * 8];
#pragma unroll
      for (int m = 0; m < 4; ++m)
#pragma unroll
        for (int n = 0; n < 4; ++n)
          acc[m][n] = __builtin_amdgcn_mfma_f32_16x16x32_bf16(af[m], bfr[n], acc[m][n], 0, 0, 0);
    }
    __syncthreads();
  }

#pragma unroll
  for (int m = 0; m < 4; ++m) {
#pragma unroll
    for (int n = 0; n < 4; ++n) {
      const int row = row0 + wr * 64 + m * 16 + lhi * 4;
      const int col = col0 + wc * 64 + n * 16 + lrow;
#pragma unroll
      for (int r = 0; r < 4; ++r)
        out[(size_t)(row + r) * OUTF + col] = acc[m][n][r];
    }
  }
}

extern "C" void kernel_launch(void* const* d_in, const int* in_sizes, int n_in,
                              void* d_out, int out_size, void* d_ws, size_t ws_size,
                              hipStream_t stream) {
  const float* x   = (const float*)d_in[0];
  const float* w_b = (const float*)d_in[1];
  const float* w_s = (const float*)d_in[2];
  const float* c   = (const float*)d_in[3];
  float* out = (float*)d_out;

  const size_t need = (size_t)OUTF * KTOT * sizeof(unsigned short);  // 10.1 MiB
  if (ws_size >= need) {
    unsigned short* bext = (unsigned short*)d_ws;
    build_bext<<<(OUTF * KTOT / 8) / 256, 256, 0, stream>>>(w_b, w_s, c, bext);
    kan_gemm2<<<(BATCH / BM) * (OUTF / BN), 256, 0, stream>>>(x, bext, out);
  } else {
    kan_gemm_fb<<<(BATCH / BM) * (OUTF / BN), 256, 0, stream>>>(x, w_b, w_s, c, out);
  }
}

// Round 4
// 253.940 us; speedup vs baseline: 3.0026x; 1.0856x over previous
//
#include <hip/hip_runtime.h>
#include <hip/hip_bf16.h>

#define BATCH 16384
#define INF 768
#define OUTF 768
#define NSLAB 9                  // slab order per ib: {8=silu, 0..7=rbf}
#define KTOT (NSLAB * INF)       // 6912
#define BM 128
#define BN 128
#define BK 64
#define PK (BK + 8)              // A-tile pad: 144B row stride
#define KB_TILES (INF / BK)      // 12
#define NIT (NSLAB * KB_TILES)   // 108

#define LOG2E 1.4426950408889634f
#define EXPM2 0.13533528323661270f   // exp(-2)

typedef __bf16 bf16x8 __attribute__((ext_vector_type(8)));
typedef float f32x4 __attribute__((ext_vector_type(4)));
typedef unsigned short ushort8v __attribute__((ext_vector_type(8)));

__device__ __forceinline__ unsigned short f2bf(float f) {
  unsigned u = __builtin_bit_cast(unsigned, f);
  u += 0x7fffu + ((u >> 16) & 1u);     // RTNE
  return (unsigned short)(u >> 16);
}

__device__ __forceinline__ unsigned cvt2(float a, float b) {
  __hip_bfloat162 h = __float22bfloat162_rn(make_float2(a, b));  // v_cvt_pk_bf16_f32
  unsigned r;
  __builtin_memcpy(&r, &h, 4);
  return r;
}

__device__ __forceinline__ void gload_lds16(const void* g, void* l) {
  __builtin_amdgcn_global_load_lds(
      (const __attribute__((address_space(1))) unsigned int*)g,
      (__attribute__((address_space(3))) unsigned int*)l, 16, 0, 0);
}

// ---------------- kernel 1: build W_ext (bf16) into workspace ----------------
__global__ __launch_bounds__(256) void build_bext(
    const float* __restrict__ w_b, const float* __restrict__ w_s,
    const float* __restrict__ c, unsigned short* __restrict__ bext) {
  const int tid = blockIdx.x * 256 + threadIdx.x;
  const int o = tid / (KTOT / 8);
  const int k = (tid - o * (KTOT / 8)) * 8;
  const int a = k / INF;
  const int i = k - a * INF;
  float4 v0, v1;
  if (a < 8) {
    const float* cp = c + ((size_t)(a * OUTF + o)) * INF + i;
    const float* wp = w_s + (size_t)o * INF + i;
    const float4 c0 = *(const float4*)cp, c1 = *(const float4*)(cp + 4);
    const float4 s0 = *(const float4*)wp, s1 = *(const float4*)(wp + 4);
    v0 = make_float4(c0.x * s0.x, c0.y * s0.y, c0.z * s0.z, c0.w * s0.w);
    v1 = make_float4(c1.x * s1.x, c1.y * s1.y, c1.z * s1.z, c1.w * s1.w);
  } else {
    const float* bp = w_b + (size_t)o * INF + i;
    v0 = *(const float4*)bp;
    v1 = *(const float4*)(bp + 4);
  }
  ushort8v r;
  r[0] = f2bf(v0.x); r[1] = f2bf(v0.y); r[2] = f2bf(v0.z); r[3] = f2bf(v0.w);
  r[4] = f2bf(v1.x); r[5] = f2bf(v1.y); r[6] = f2bf(v1.z); r[7] = f2bf(v1.w);
  *(ushort8v*)(bext + (size_t)o * KTOT + k) = r;
}

// ------- kernel 2: dbuf MFMA GEMM, recurrence A-expansion, 1 barrier/iter -----
__global__ __launch_bounds__(256, 2) void kan_gemm3(
    const float* __restrict__ x, const unsigned short* __restrict__ bext,
    float* __restrict__ out) {
  __shared__ unsigned short As[2][BM][PK];   // 2 x 18 KiB, ds_write staged (padded)
  __shared__ unsigned short Bs[2][BN * BK];  // 2 x 16 KiB, global_load_lds (XOR swz)

  const int orig = blockIdx.x;
  const int bid = (orig & 7) * 96 + (orig >> 3);   // bijective XCD swizzle (768=8*96)
  const int cb = bid / (BATCH / BM);               // cb-major: XCD chunk shares B-strip
  const int rb = bid - cb * (BATCH / BM);
  const int row0 = rb * BM, col0 = cb * BN;

  const int t = threadIdx.x;
  const int lane = t & 63;
  const int w = t >> 6;
  const int wr = w >> 1, wc = w & 1;               // 2x2 waves, 64x64 each
  const int lrow = lane & 15, lhi = lane >> 4;
  const int rgrp = lane >> 3, ch = lane & 7;       // B staging lane decomposition

  f32x4 acc[4][4];
#pragma unroll
  for (int m = 0; m < 4; ++m)
#pragma unroll
    for (int n = 0; n < 4; ++n)
      acc[m][n] = (f32x4){0.f, 0.f, 0.f, 0.f};

  const int rsub = t >> 4;   // 0..15
  const int k4 = t & 15;

  // B global src pre-swizzled (chunk ^ row) so linear LDS realizes XOR layout.
  const unsigned short* gB0 =
      bext + (size_t)(col0 + w * 32 + rgrp) * KTOT + (size_t)(ch ^ rgrp) * 8;

  f32x4 ph[8], gg[8];   // recurrence state: phi_a, G_a per owned element

  auto stage_b = [&](int kt, int bb) {
    const unsigned short* gB = gB0 + (size_t)kt * BK;
    unsigned short* l = &Bs[bb][w * 2048];
#pragma unroll
    for (int q = 0; q < 4; ++q)
      gload_lds16(gB + (size_t)q * 8 * KTOT, l + q * 512);
  };

  auto stage_a8 = [&](int ib, int bb) {   // silu slab + phi/G setup (x loaded once)
#pragma unroll
    for (int p = 0; p < 8; ++p) {
      const f32x4 xv = *(const f32x4*)(x + (size_t)(row0 + p * 16 + rsub) * INF +
                                       ib * BK + k4 * 4);
      f32x4 s;
#pragma unroll
      for (int e = 0; e < 4; ++e) {
        const float ex = __builtin_amdgcn_exp2f(xv[e] * (-LOG2E));   // exp(-x)
        s[e] = xv[e] * __builtin_amdgcn_rcpf(1.f + ex);              // silu
      }
      *(uint2*)&As[bb][p * 16 + rsub][k4 * 4] =
          make_uint2(cvt2(s[0], s[1]), cvt2(s[2], s[3]));
      const f32x4 z = xv * 1.75f + 3.5f;      // z0 = (x - g0)/h
      const f32x4 zz = z * z;
#pragma unroll
      for (int e = 0; e < 4; ++e) {
        ph[p][e] = __builtin_amdgcn_exp2f(zz[e] * (-LOG2E));                 // exp(-z0^2)
        gg[p][e] = __builtin_amdgcn_exp2f(z[e] * (2.f * LOG2E) - LOG2E);     // exp(2z0-1)
      }
    }
  };

  auto stage_ar = [&](int bb) {   // rbf slab: write phi_a, advance recurrence
#pragma unroll
    for (int p = 0; p < 8; ++p) {
      const f32x4 v = ph[p];
      *(uint2*)&As[bb][p * 16 + rsub][k4 * 4] =
          make_uint2(cvt2(v[0], v[1]), cvt2(v[2], v[3]));
      ph[p] = v * gg[p];          // phi_{a+1} = phi_a * G_a
      gg[p] = gg[p] * EXPM2;      // G_{a+1} = G_a * exp(-2)
    }
  };

  // prologue: stage (slab 8, ib 0) into buf 0
  stage_b(8 * KB_TILES + 0, 0);
  stage_a8(0, 0);

  int s_n = 0, ib_n = 0;   // next slab to stage; per-ib order: 8,0,1,...,7
  for (int it = 0; it < NIT; ++it) {
    const int cur = it & 1;
    __syncthreads();   // buf[cur] staged & prior reads of buf[cur^1] done
    if (it < NIT - 1) {
      stage_b(s_n * KB_TILES + ib_n, cur ^ 1);
      if (s_n == 8) stage_a8(ib_n, cur ^ 1);
      else          stage_ar(cur ^ 1);
      if (s_n == 7)      { s_n = 8; ib_n++; }
      else if (s_n == 8) { s_n = 0; }
      else               { s_n++; }
    }
#pragma unroll
    for (int kk = 0; kk < 2; ++kk) {
      bf16x8 af[4], bfr[4];
#pragma unroll
      for (int m = 0; m < 4; ++m)
        af[m] = *(const bf16x8*)&As[cur][wr * 64 + m * 16 + lrow][kk * 32 + lhi * 8];
#pragma unroll
      for (int n = 0; n < 4; ++n) {
        const int rowB = wc * 64 + n * 16 + lrow;
        const int chB = (kk * 4 + lhi) ^ (lrow & 7);
        bfr[n] = *(const bf16x8*)&Bs[cur][rowB * 64 + chB * 8];
      }
#pragma unroll
      for (int m = 0; m < 4; ++m)
#pragma unroll
        for (int n = 0; n < 4; ++n)
          acc[m][n] = __builtin_amdgcn_mfma_f32_16x16x32_bf16(af[m], bfr[n], acc[m][n], 0, 0, 0);
    }
  }

  // epilogue: C/D layout col=lane&15, row=(lane>>4)*4+r
#pragma unroll
  for (int m = 0; m < 4; ++m) {
#pragma unroll
    for (int n = 0; n < 4; ++n) {
      const int row = row0 + wr * 64 + m * 16 + lhi * 4;
      const int col = col0 + wc * 64 + n * 16 + lrow;
#pragma unroll
      for (int r = 0; r < 4; ++r)
        out[(size_t)(row + r) * OUTF + col] = acc[m][n][r];
    }
  }
}

// ---------------- fallback if ws too small (round-1 kernel) ------------------
__device__ __forceinline__ float phi_f(float x, float g) {
  float z = (x - g) * 1.75f;
  return __expf(-z * z);
}
__device__ __forceinline__ float silu_f(float x) {
  return x / (1.f + __expf(-x));
}

__global__ __launch_bounds__(256, 2) void kan_gemm_fb(
    const float* __restrict__ x, const float* __restrict__ w_b,
    const float* __restrict__ w_s, const float* __restrict__ c,
    float* __restrict__ out) {
  __shared__ unsigned short As[BM][PK];
  __shared__ unsigned short Bs[BN][PK];

  const int bid = blockIdx.x;
  const int cb = bid % (OUTF / BN);
  const int rb = bid / (OUTF / BN);
  const int row0 = rb * BM, col0 = cb * BN;

  const int t = threadIdx.x;
  const int lane = t & 63;
  const int w = t >> 6;
  const int wr = w >> 1, wc = w & 1;
  const int lrow = lane & 15, lhi = lane >> 4;

  f32x4 acc[4][4];
#pragma unroll
  for (int m = 0; m < 4; ++m)
#pragma unroll
    for (int n = 0; n < 4; ++n)
      acc[m][n] = (f32x4){0.f, 0.f, 0.f, 0.f};

  const int rsub = t >> 4;
  const int k4 = t & 15;

  for (int kt = 0; kt < KTOT / BK; ++kt) {
    const int a = kt / KB_TILES;
    const int i0 = (kt % KB_TILES) * BK;
    const float ga = -2.f + (float)a * (4.f / 7.f);

#pragma unroll
    for (int p = 0; p < 8; ++p) {
      const int r = p * 16 + rsub;
      const float4 xv = *(const float4*)(x + (size_t)(row0 + r) * INF + i0 + k4 * 4);
      ushort4 av;
      if (a < 8) {
        av.x = f2bf(phi_f(xv.x, ga)); av.y = f2bf(phi_f(xv.y, ga));
        av.z = f2bf(phi_f(xv.z, ga)); av.w = f2bf(phi_f(xv.w, ga));
      } else {
        av.x = f2bf(silu_f(xv.x)); av.y = f2bf(silu_f(xv.y));
        av.z = f2bf(silu_f(xv.z)); av.w = f2bf(silu_f(xv.w));
      }
      *(ushort4*)&As[r][k4 * 4] = av;

      ushort4 bv;
      if (a < 8) {
        const float4 cv = *(const float4*)(c + ((size_t)a * OUTF + col0 + r) * INF + i0 + k4 * 4);
        const float4 wv = *(const float4*)(w_s + (size_t)(col0 + r) * INF + i0 + k4 * 4);
        bv.x = f2bf(cv.x * wv.x); bv.y = f2bf(cv.y * wv.y);
        bv.z = f2bf(cv.z * wv.z); bv.w = f2bf(cv.w * wv.w);
      } else {
        const float4 bbv = *(const float4*)(w_b + (size_t)(col0 + r) * INF + i0 + k4 * 4);
        bv.x = f2bf(bbv.x); bv.y = f2bf(bbv.y);
        bv.z = f2bf(bbv.z); bv.w = f2bf(bbv.w);
      }
      *(ushort4*)&Bs[r][k4 * 4] = bv;
    }
    __syncthreads();

#pragma unroll
    for (int kk = 0; kk < 2; ++kk) {
      bf16x8 af[4], bfr[4];
#pragma unroll
      for (int m = 0; m < 4; ++m)
        af[m] = *(const bf16x8*)&As[wr * 64 + m * 16 + lrow][kk * 32 + lhi * 8];
#pragma unroll
      for (int n = 0; n < 4; ++n)
        bfr[n] = *(const bf16x8*)&Bs[wc * 64 + n * 16 + lrow][kk * 32 + lhi * 8];
#pragma unroll
      for (int m = 0; m < 4; ++m)
#pragma unroll
        for (int n = 0; n < 4; ++n)
          acc[m][n] = __builtin_amdgcn_mfma_f32_16x16x32_bf16(af[m], bfr[n], acc[m][n], 0, 0, 0);
    }
    __syncthreads();
  }

#pragma unroll
  for (int m = 0; m < 4; ++m) {
#pragma unroll
    for (int n = 0; n < 4; ++n) {
      const int row = row0 + wr * 64 + m * 16 + lhi * 4;
      const int col = col0 + wc * 64 + n * 16 + lrow;
#pragma unroll
      for (int r = 0; r < 4; ++r)
        out[(size_t)(row + r) * OUTF + col] = acc[m][n][r];
    }
  }
}

extern "C" void kernel_launch(void* const* d_in, const int* in_sizes, int n_in,
                              void* d_out, int out_size, void* d_ws, size_t ws_size,
                              hipStream_t stream) {
  const float* x   = (const float*)d_in[0];
  const float* w_b = (const float*)d_in[1];
  const float* w_s = (const float*)d_in[2];
  const float* c   = (const float*)d_in[3];
  float* out = (float*)d_out;

  const size_t need = (size_t)OUTF * KTOT * sizeof(unsigned short);  // 10.1 MiB
  if (ws_size >= need) {
    unsigned short* bext = (unsigned short*)d_ws;
    build_bext<<<(OUTF * KTOT / 8) / 256, 256, 0, stream>>>(w_b, w_s, c, bext);
    kan_gemm3<<<(BATCH / BM) * (OUTF / BN), 256, 0, stream>>>(x, bext, out);
  } else {
    kan_gemm_fb<<<(BATCH / BM) * (OUTF / BN), 256, 0, stream>>>(x, w_b, w_s, c, out);
  }
}